// Round 2
// baseline (225.351 us; speedup 1.0000x reference)
//
#include <hip/hip_runtime.h>
#include <math.h>

#define NQ 22
#define NH 9        // high qubits 0..8   (h = x >> 13)
#define NL 13       // low qubits 9..21   (l = x & 8191)
#define HD 512
#define LD 8192

// In-register butterfly over register-index bit K (32 regs -> 16 pairs).
template<int K>
__device__ __forceinline__ void bfly32(float v[32], float2 cc) {
    const float c = cc.x, s = cc.y;
#pragma unroll
    for (int p = 0; p < 16; ++p) {
        int i0 = ((p >> K) << (K + 1)) | (p & ((1 << K) - 1));
        int i1 = i0 | (1 << K);
        float a = v[i0], b = v[i1];
        v[i0] = c * a - s * b;
        v[i1] = s * a + c * b;
    }
}

// ---------------- K0: tables + zero out ----------------
__global__ void k0_tables(const float* feat, const float* adj, const float* params,
                          float* w, float* u, unsigned* sigh, unsigned* lowvs,
                          float2* cs1, float2* cs2, float* out) {
    int t = blockIdx.x * blockDim.x + threadIdx.x;
    if (t < NQ) {
        cs1[t] = make_float2(cosf(0.5f * params[NQ + t]),   sinf(0.5f * params[NQ + t]));
        cs2[t] = make_float2(cosf(0.5f * params[2*NQ + t]), sinf(0.5f * params[2*NQ + t]));
        out[t] = 0.f;
    }
    if (t < HD) {
        int h = t;
        unsigned par = 0;
        float prod = 1.f;
        for (int i = 0; i < NH; i++) {
            int bi = (h >> (NH - 1 - i)) & 1;
            float a = 0.5f * (feat[i] + params[i]);
            prod *= bi ? sinf(a) : cosf(a);
            if (bi) {
                for (int j2 = i + 1; j2 < NH; j2++)
                    if (((h >> (NH - 1 - j2)) & 1) && adj[i * NQ + j2] > 0.f) par ^= 1u;
            }
        }
        w[h] = prod;
        sigh[h] = par;
    }
    if (t < LD) {
        int l = t;
        unsigned par = 0;
        float prod = 1.f;
        for (int qi = 0; qi < NL; qi++) {
            int q = NH + qi;
            int b = (l >> (NQ - 1 - q)) & 1;
            float a = 0.5f * (feat[q] + params[q]);
            prod *= b ? sinf(a) : cosf(a);
            if (b) {
                for (int qj = qi + 1; qj < NL; qj++) {
                    int q2 = NH + qj;
                    if (((l >> (NQ - 1 - q2)) & 1) && adj[q * NQ + q2] > 0.f) par ^= 1u;
                }
            }
        }
        unsigned V = 0;
        for (int i = 0; i < NH; i++) {
            unsigned p2 = 0;
            for (int qj = 0; qj < NL; qj++) {
                int q2 = NH + qj;
                if (((l >> (NQ - 1 - q2)) & 1) && adj[i * NQ + q2] > 0.f) p2 ^= 1u;
            }
            V |= p2 << (NH - 1 - i);
        }
        u[l] = prod;
        lowvs[l] = V | (par << NH);
    }
}

// ---------------- kA: init (feat+p0+sign) + layer-1 low, all butterflies in regs ----------
// Mappings (l within the 8192-chunk of row h), thread t, reg r:
//   A : l = r + 32*t            (reg bits = l bits 0-4, qubits 21..17)
//   B : l = (t&31)+32*r+1024*(t>>5)  (reg bits = l bits 5-9, qubits 16..12)
//   C': l = 4*t + (r&3) + 1024*(r>>2) (reg bits 2-4 = l bits 10-12, qubits 11..9)
// LDS layout f(l) = l + (l>>5)  (all mapped patterns <=2-way conflict: free)
__global__ __launch_bounds__(256) void kA(float* state, const float* w, const float* u,
                                          const unsigned* sigh, const unsigned* lowvs,
                                          const float2* cs1) {
    __shared__ float chunk[8448];
    const int h = blockIdx.x, t = threadIdx.x;

    // stage sign(h,l)*u[l] into LDS (coalesced global reads)
#pragma unroll
    for (int it = 0; it < 32; ++it) {
        int i = t + 256 * it;
        unsigned lv = lowvs[i];
        float uv = u[i];
        unsigned sgn = ((lv >> NH) ^ (unsigned)__popc(h & (lv & 511u))) & 1u;
        chunk[i + (i >> 5)] = sgn ? -uv : uv;
    }
    float whs = sigh[h] ? -w[h] : w[h];
    __syncthreads();

    float v[32];
#pragma unroll
    for (int r = 0; r < 32; ++r) v[r] = whs * chunk[r + 33 * t];   // mapping A

    bfly32<0>(v, cs1[21]); bfly32<1>(v, cs1[20]); bfly32<2>(v, cs1[19]);
    bfly32<3>(v, cs1[18]); bfly32<4>(v, cs1[17]);

    __syncthreads();
#pragma unroll
    for (int r = 0; r < 32; ++r) chunk[r + 33 * t] = v[r];
    __syncthreads();
    const int t5 = t & 31, th = t >> 5;
#pragma unroll
    for (int r = 0; r < 32; ++r) v[r] = chunk[t5 + 33 * r + 1056 * th];  // mapping B

    bfly32<0>(v, cs1[16]); bfly32<1>(v, cs1[15]); bfly32<2>(v, cs1[14]);
    bfly32<3>(v, cs1[13]); bfly32<4>(v, cs1[12]);

    __syncthreads();
#pragma unroll
    for (int r = 0; r < 32; ++r) chunk[t5 + 33 * r + 1056 * th] = v[r];
    __syncthreads();
#pragma unroll
    for (int r = 0; r < 32; ++r) {
        int l = 4 * t + (r & 3) + 1024 * (r >> 2);                  // mapping C'
        v[r] = chunk[l + (l >> 5)];
    }

    bfly32<2>(v, cs1[11]); bfly32<3>(v, cs1[10]); bfly32<4>(v, cs1[9]);

    float4* sp = (float4*)(state + (size_t)h * LD + 4 * t);
#pragma unroll
    for (int r5 = 0; r5 < 8; ++r5)
        sp[r5 * 256] = make_float4(v[4*r5], v[4*r5+1], v[4*r5+2], v[4*r5+3]);
}

// ---------------- kB: layer-1 high + sign + layer-2 high (fused column pass) ----------
// Block owns cols rb..rb+15 (all 512 h). t = j + 16*g.
//   beta : m = r + 32*g   (reg bits = m bits 0-4; stages k=0..3 -> qubits 8..5)
//   alpha: m = g + 16*r   (reg bits = m bits 4-8; stages k=0..4 -> qubits 4..0)
// LDS layout f(m,j) = 17*m + j.
__global__ __launch_bounds__(256) void kB(float* state, const unsigned* sigh,
                                          const unsigned* lowvs,
                                          const float2* cs1, const float2* cs2) {
    __shared__ float tile[8704];
    __shared__ unsigned sgh[HD];
    const int t = threadIdx.x;
    const int j = t & 15, g = t >> 4;
    const int rb = blockIdx.x * 16;

    sgh[t] = sigh[t]; sgh[t + 256] = sigh[t + 256];

    float v[32];
    const float* gp = state + (size_t)(32 * g) * LD + rb + j;
#pragma unroll
    for (int r = 0; r < 32; ++r) v[r] = gp[(size_t)r * LD];         // beta

    // layer-1 high, beta part (qubits 8..5)
    bfly32<0>(v, cs1[8]); bfly32<1>(v, cs1[7]); bfly32<2>(v, cs1[6]); bfly32<3>(v, cs1[5]);

    __syncthreads();   // also covers sgh staging
#pragma unroll
    for (int r = 0; r < 32; ++r) tile[(r + 32 * g) * 17 + j] = v[r];
    __syncthreads();
#pragma unroll
    for (int r = 0; r < 32; ++r) v[r] = tile[(g + 16 * r) * 17 + j];  // alpha

    // layer-1 high, alpha part (qubits 4..0)
    bfly32<0>(v, cs1[4]); bfly32<1>(v, cs1[3]); bfly32<2>(v, cs1[2]);
    bfly32<3>(v, cs1[1]); bfly32<4>(v, cs1[0]);

    // sign between layer 1 and layer 2
    {
        unsigned lv = lowvs[rb + j];
        unsigned V = lv & 511u, sl = (lv >> NH) & 1u;
#pragma unroll
        for (int r = 0; r < 32; ++r) {
            int m = g + 16 * r;
            unsigned sgn = (sgh[m] ^ sl ^ (unsigned)__popc((unsigned)m & V)) & 1u;
            if (sgn) v[r] = -v[r];
        }
    }

    // layer-2 high, alpha part
    bfly32<0>(v, cs2[4]); bfly32<1>(v, cs2[3]); bfly32<2>(v, cs2[2]);
    bfly32<3>(v, cs2[1]); bfly32<4>(v, cs2[0]);

    __syncthreads();
#pragma unroll
    for (int r = 0; r < 32; ++r) tile[(g + 16 * r) * 17 + j] = v[r];
    __syncthreads();
#pragma unroll
    for (int r = 0; r < 32; ++r) v[r] = tile[(r + 32 * g) * 17 + j];  // beta

    // layer-2 high, beta part
    bfly32<0>(v, cs2[8]); bfly32<1>(v, cs2[7]); bfly32<2>(v, cs2[6]); bfly32<3>(v, cs2[5]);

    float* op = state + (size_t)(32 * g) * LD + rb + j;
#pragma unroll
    for (int r = 0; r < 32; ++r) op[(size_t)r * LD] = v[r];
}

// ---------------- kC: layer-2 low + probs + all 22 expectation partials ----------
__global__ __launch_bounds__(256) void kC(const float* state, const float2* cs2, float* out) {
    __shared__ float chunk[8448];
    __shared__ float wred[4][12];
    const int h = blockIdx.x, t = threadIdx.x;

    float v[32];
    const float4* sp = (const float4*)(state + (size_t)h * LD + 4 * t);
#pragma unroll
    for (int r5 = 0; r5 < 8; ++r5) {
        float4 x = sp[r5 * 256];
        v[4*r5] = x.x; v[4*r5+1] = x.y; v[4*r5+2] = x.z; v[4*r5+3] = x.w;  // C'
    }

    bfly32<2>(v, cs2[11]); bfly32<3>(v, cs2[10]); bfly32<4>(v, cs2[9]);

#pragma unroll
    for (int r = 0; r < 32; ++r) {
        int l = 4 * t + (r & 3) + 1024 * (r >> 2);
        chunk[l + (l >> 5)] = v[r];
    }
    __syncthreads();
    const int t5 = t & 31, th = t >> 5;
#pragma unroll
    for (int r = 0; r < 32; ++r) v[r] = chunk[t5 + 33 * r + 1056 * th];  // B

    bfly32<0>(v, cs2[16]); bfly32<1>(v, cs2[15]); bfly32<2>(v, cs2[14]);
    bfly32<3>(v, cs2[13]); bfly32<4>(v, cs2[12]);

    __syncthreads();
#pragma unroll
    for (int r = 0; r < 32; ++r) chunk[t5 + 33 * r + 1056 * th] = v[r];
    __syncthreads();
#pragma unroll
    for (int r = 0; r < 32; ++r) v[r] = chunk[r + 33 * t];               // A

    bfly32<0>(v, cs2[21]); bfly32<1>(v, cs2[20]); bfly32<2>(v, cs2[19]);
    bfly32<3>(v, cs2[18]); bfly32<4>(v, cs2[17]);

    // probs
#pragma unroll
    for (int r = 0; r < 32; ++r) v[r] = v[r] * v[r];

    // per-thread partials. Mapping A: l = r + 32*t; reg bit k -> qubit 21-k;
    // t bit i (i=0..7) -> l bit 5+i -> qubit 16-i.
    float tot = 0.f;
#pragma unroll
    for (int r = 0; r < 32; ++r) tot += v[r];
    float s5[5];
#pragma unroll
    for (int k = 0; k < 5; ++k) {
        float a = 0.f;
#pragma unroll
        for (int r = 0; r < 32; ++r) a += ((r >> k) & 1) ? -v[r] : v[r];
        s5[k] = a;
    }
    const int lane = t & 63, wv = t >> 6;
    float st6[6];
#pragma unroll
    for (int i = 0; i < 6; ++i) st6[i] = ((lane >> i) & 1) ? -tot : tot;

#pragma unroll
    for (int off = 32; off > 0; off >>= 1) {
        tot += __shfl_down(tot, off, 64);
#pragma unroll
        for (int k = 0; k < 5; ++k) s5[k] += __shfl_down(s5[k], off, 64);
#pragma unroll
        for (int i = 0; i < 6; ++i) st6[i] += __shfl_down(st6[i], off, 64);
    }
    if (lane == 0) {
        wred[wv][0] = tot;
#pragma unroll
        for (int k = 0; k < 5; ++k) wred[wv][1 + k] = s5[k];
#pragma unroll
        for (int i = 0; i < 6; ++i) wred[wv][6 + i] = st6[i];
    }
    __syncthreads();
    if (t == 0) {
        float bt = 0.f, a5[5] = {0,0,0,0,0}, a6[6] = {0,0,0,0,0,0}, a10 = 0.f, a9 = 0.f;
#pragma unroll
        for (int w2 = 0; w2 < 4; ++w2) {
            float wt = wred[w2][0];
            bt += wt;
#pragma unroll
            for (int k = 0; k < 5; ++k) a5[k] += wred[w2][1 + k];
#pragma unroll
            for (int i = 0; i < 6; ++i) a6[i] += wred[w2][6 + i];
            a10 += (w2 & 1) ? -wt : wt;        // t bit 6 -> qubit 10
            a9  += ((w2 >> 1) & 1) ? -wt : wt; // t bit 7 -> qubit 9
        }
#pragma unroll
        for (int q = 0; q < 9; ++q)
            atomicAdd(&out[q], ((h >> (8 - q)) & 1) ? -bt : bt);
        atomicAdd(&out[9], a9);
        atomicAdd(&out[10], a10);
#pragma unroll
        for (int i = 0; i < 6; ++i) atomicAdd(&out[16 - i], a6[i]);
#pragma unroll
        for (int k = 0; k < 5; ++k) atomicAdd(&out[21 - k], a5[k]);
    }
}

extern "C" void kernel_launch(void* const* d_in, const int* in_sizes, int n_in,
                              void* d_out, int out_size, void* d_ws, size_t ws_size,
                              hipStream_t stream) {
    const float* feat   = (const float*)d_in[0];   // 22
    const float* adj    = (const float*)d_in[1];   // 22*22
    const float* params = (const float*)d_in[2];   // 3*22
    float* out = (float*)d_out;                    // 22 f32

    char* ws = (char*)d_ws;
    float*    state  = (float*)ws;                              // 4M floats = 16 MB
    float*    w      = (float*)(ws + ((size_t)1 << 24));        // 512
    float*    u      = w + HD;                                  // 8192
    unsigned* sigh   = (unsigned*)(u + LD);                     // 512
    unsigned* lowvs  = sigh + HD;                               // 8192
    float2*   cs1    = (float2*)(lowvs + LD);                   // 22
    float2*   cs2    = cs1 + NQ;                                // 22

    k0_tables<<<dim3(32), dim3(256), 0, stream>>>(feat, adj, params, w, u, sigh, lowvs,
                                                  cs1, cs2, out);
    kA<<<dim3(512), dim3(256), 0, stream>>>(state, w, u, sigh, lowvs, cs1);
    kB<<<dim3(512), dim3(256), 0, stream>>>(state, sigh, lowvs, cs1, cs2);
    kC<<<dim3(512), dim3(256), 0, stream>>>(state, cs2, out);
}

// Round 3
// 130.522 us; speedup vs baseline: 1.7265x; 1.7265x over previous
//
#include <hip/hip_runtime.h>
#include <math.h>

#define NQ 22
#define NH 9        // high qubits 0..8   (h = x >> 13)
#define NL 13       // low qubits 9..21   (l = x & 8191)
#define HD 512
#define LD 8192

// In-register butterfly over register-index bit K (32 regs -> 16 pairs).
template<int K>
__device__ __forceinline__ void bfly32(float v[32], float2 cc) {
    const float c = cc.x, s = cc.y;
#pragma unroll
    for (int p = 0; p < 16; ++p) {
        int i0 = ((p >> K) << (K + 1)) | (p & ((1 << K) - 1));
        int i1 = i0 | (1 << K);
        float a = v[i0], b = v[i1];
        v[i0] = c * a - s * b;
        v[i1] = s * a + c * b;
    }
}

// ---------------- K0: tables + zero out ----------------
__global__ void k0_tables(const float* feat, const float* adj, const float* params,
                          float* w, float* u, unsigned* sigh, unsigned* lowvs,
                          float2* cs1, float2* cs2, float* out) {
    int t = blockIdx.x * blockDim.x + threadIdx.x;
    if (t < NQ) {
        cs1[t] = make_float2(cosf(0.5f * params[NQ + t]),   sinf(0.5f * params[NQ + t]));
        cs2[t] = make_float2(cosf(0.5f * params[2*NQ + t]), sinf(0.5f * params[2*NQ + t]));
        out[t] = 0.f;
    }
    if (t < HD) {
        int h = t;
        unsigned par = 0;
        float prod = 1.f;
        for (int i = 0; i < NH; i++) {
            int bi = (h >> (NH - 1 - i)) & 1;
            float a = 0.5f * (feat[i] + params[i]);
            prod *= bi ? sinf(a) : cosf(a);
            if (bi) {
                for (int j2 = i + 1; j2 < NH; j2++)
                    if (((h >> (NH - 1 - j2)) & 1) && adj[i * NQ + j2] > 0.f) par ^= 1u;
            }
        }
        w[h] = prod;
        sigh[h] = par;
    }
    if (t < LD) {
        int l = t;
        unsigned par = 0;
        float prod = 1.f;
        for (int qi = 0; qi < NL; qi++) {
            int q = NH + qi;
            int b = (l >> (NQ - 1 - q)) & 1;
            float a = 0.5f * (feat[q] + params[q]);
            prod *= b ? sinf(a) : cosf(a);
            if (b) {
                for (int qj = qi + 1; qj < NL; qj++) {
                    int q2 = NH + qj;
                    if (((l >> (NQ - 1 - q2)) & 1) && adj[q * NQ + q2] > 0.f) par ^= 1u;
                }
            }
        }
        unsigned V = 0;
        for (int i = 0; i < NH; i++) {
            unsigned p2 = 0;
            for (int qj = 0; qj < NL; qj++) {
                int q2 = NH + qj;
                if (((l >> (NQ - 1 - q2)) & 1) && adj[i * NQ + q2] > 0.f) p2 ^= 1u;
            }
            V |= p2 << (NH - 1 - i);
        }
        u[l] = prod;
        lowvs[l] = V | (par << NH);
    }
}

// ---------------- kA: init (feat+p0+sign) + layer-1 low ----------
// Mappings (l within the 8192-chunk of row h), thread t, reg r:
//   A : l = r + 32*t                 (reg bits = l bits 0-4, qubits 21..17)
//   B : l = (t&31)+32*r+1024*(t>>5)  (reg bits = l bits 5-9, qubits 16..12)
//   C': l = 4*t + (r&3) + 1024*(r>>2)(reg bits 2-4 = l bits 10-12, qubits 11..9)
// LDS layout f(l) = l + (l>>5)  (all mapped patterns <=2-way conflict: free)
// launch_bounds (256,4): 128-VGPR cap -- v[32] must stay in registers (R2's
// 1-arg bounds capped at ~52 VGPR and spilled the array -> 2x slowdown).
__global__ __launch_bounds__(256, 4) void kA(float* state, const float* w, const float* u,
                                             const unsigned* sigh, const unsigned* lowvs,
                                             const float2* cs1) {
    __shared__ float chunk[8448];
    const int h = blockIdx.x, t = threadIdx.x;

#pragma unroll
    for (int it = 0; it < 32; ++it) {
        int i = t + 256 * it;
        unsigned lv = lowvs[i];
        float uv = u[i];
        unsigned sgn = ((lv >> NH) ^ (unsigned)__popc(h & (lv & 511u))) & 1u;
        chunk[i + (i >> 5)] = sgn ? -uv : uv;
    }
    float whs = sigh[h] ? -w[h] : w[h];
    __syncthreads();

    float v[32];
#pragma unroll
    for (int r = 0; r < 32; ++r) v[r] = whs * chunk[r + 33 * t];   // mapping A

    bfly32<0>(v, cs1[21]); bfly32<1>(v, cs1[20]); bfly32<2>(v, cs1[19]);
    bfly32<3>(v, cs1[18]); bfly32<4>(v, cs1[17]);

    __syncthreads();
#pragma unroll
    for (int r = 0; r < 32; ++r) chunk[r + 33 * t] = v[r];
    __syncthreads();
    const int t5 = t & 31, th = t >> 5;
#pragma unroll
    for (int r = 0; r < 32; ++r) v[r] = chunk[t5 + 33 * r + 1056 * th];  // mapping B

    bfly32<0>(v, cs1[16]); bfly32<1>(v, cs1[15]); bfly32<2>(v, cs1[14]);
    bfly32<3>(v, cs1[13]); bfly32<4>(v, cs1[12]);

    __syncthreads();
#pragma unroll
    for (int r = 0; r < 32; ++r) chunk[t5 + 33 * r + 1056 * th] = v[r];
    __syncthreads();
#pragma unroll
    for (int r = 0; r < 32; ++r) {
        int l = 4 * t + (r & 3) + 1024 * (r >> 2);                  // mapping C'
        v[r] = chunk[l + (l >> 5)];
    }

    bfly32<2>(v, cs1[11]); bfly32<3>(v, cs1[10]); bfly32<4>(v, cs1[9]);

    float4* sp = (float4*)(state + (size_t)h * LD + 4 * t);
#pragma unroll
    for (int r5 = 0; r5 < 8; ++r5)
        sp[r5 * 256] = make_float4(v[4*r5], v[4*r5+1], v[4*r5+2], v[4*r5+3]);
}

// ---------------- kB: layer-1 high + sign + layer-2 high (fused column pass) ----------
__global__ __launch_bounds__(256, 4) void kB(float* state, const unsigned* sigh,
                                             const unsigned* lowvs,
                                             const float2* cs1, const float2* cs2) {
    __shared__ float tile[8704];
    __shared__ unsigned sgh[HD];
    const int t = threadIdx.x;
    const int j = t & 15, g = t >> 4;
    const int rb = blockIdx.x * 16;

    sgh[t] = sigh[t]; sgh[t + 256] = sigh[t + 256];

    float v[32];
    const float* gp = state + (size_t)(32 * g) * LD + rb + j;
#pragma unroll
    for (int r = 0; r < 32; ++r) v[r] = gp[(size_t)r * LD];         // beta: m = r + 32g

    bfly32<0>(v, cs1[8]); bfly32<1>(v, cs1[7]); bfly32<2>(v, cs1[6]); bfly32<3>(v, cs1[5]);

    __syncthreads();   // also covers sgh staging
#pragma unroll
    for (int r = 0; r < 32; ++r) tile[(r + 32 * g) * 17 + j] = v[r];
    __syncthreads();
#pragma unroll
    for (int r = 0; r < 32; ++r) v[r] = tile[(g + 16 * r) * 17 + j];  // alpha: m = g + 16r

    bfly32<0>(v, cs1[4]); bfly32<1>(v, cs1[3]); bfly32<2>(v, cs1[2]);
    bfly32<3>(v, cs1[1]); bfly32<4>(v, cs1[0]);

    {
        unsigned lv = lowvs[rb + j];
        unsigned V = lv & 511u, sl = (lv >> NH) & 1u;
#pragma unroll
        for (int r = 0; r < 32; ++r) {
            int m = g + 16 * r;
            unsigned sgn = (sgh[m] ^ sl ^ (unsigned)__popc((unsigned)m & V)) & 1u;
            if (sgn) v[r] = -v[r];
        }
    }

    bfly32<0>(v, cs2[4]); bfly32<1>(v, cs2[3]); bfly32<2>(v, cs2[2]);
    bfly32<3>(v, cs2[1]); bfly32<4>(v, cs2[0]);

    __syncthreads();
#pragma unroll
    for (int r = 0; r < 32; ++r) tile[(g + 16 * r) * 17 + j] = v[r];
    __syncthreads();
#pragma unroll
    for (int r = 0; r < 32; ++r) v[r] = tile[(r + 32 * g) * 17 + j];  // beta

    bfly32<0>(v, cs2[8]); bfly32<1>(v, cs2[7]); bfly32<2>(v, cs2[6]); bfly32<3>(v, cs2[5]);

    float* op = state + (size_t)(32 * g) * LD + rb + j;
#pragma unroll
    for (int r = 0; r < 32; ++r) op[(size_t)r * LD] = v[r];
}

// ---------------- kC: layer-2 low + probs + 22 expectation partials ----------
__global__ __launch_bounds__(256, 4) void kC(const float* state, const float2* cs2, float* out) {
    __shared__ float chunk[8448];
    const int h = blockIdx.x, t = threadIdx.x;

    float v[32];
    const float4* sp = (const float4*)(state + (size_t)h * LD + 4 * t);
#pragma unroll
    for (int r5 = 0; r5 < 8; ++r5) {
        float4 x = sp[r5 * 256];
        v[4*r5] = x.x; v[4*r5+1] = x.y; v[4*r5+2] = x.z; v[4*r5+3] = x.w;  // C'
    }

    bfly32<2>(v, cs2[11]); bfly32<3>(v, cs2[10]); bfly32<4>(v, cs2[9]);

#pragma unroll
    for (int r = 0; r < 32; ++r) {
        int l = 4 * t + (r & 3) + 1024 * (r >> 2);
        chunk[l + (l >> 5)] = v[r];
    }
    __syncthreads();
    const int t5 = t & 31, th = t >> 5;
#pragma unroll
    for (int r = 0; r < 32; ++r) v[r] = chunk[t5 + 33 * r + 1056 * th];  // B

    bfly32<0>(v, cs2[16]); bfly32<1>(v, cs2[15]); bfly32<2>(v, cs2[14]);
    bfly32<3>(v, cs2[13]); bfly32<4>(v, cs2[12]);

    __syncthreads();
#pragma unroll
    for (int r = 0; r < 32; ++r) chunk[t5 + 33 * r + 1056 * th] = v[r];
    __syncthreads();
#pragma unroll
    for (int r = 0; r < 32; ++r) v[r] = chunk[r + 33 * t];               // A: l = r + 32t

    bfly32<0>(v, cs2[21]); bfly32<1>(v, cs2[20]); bfly32<2>(v, cs2[19]);
    bfly32<3>(v, cs2[18]); bfly32<4>(v, cs2[17]);

    // probs + per-thread partials (6 live floats; v dead after)
#pragma unroll
    for (int r = 0; r < 32; ++r) v[r] = v[r] * v[r];
    float tot = 0.f;
#pragma unroll
    for (int r = 0; r < 32; ++r) tot += v[r];
    float s5[5];
#pragma unroll
    for (int k = 0; k < 5; ++k) {
        float a = 0.f;
#pragma unroll
        for (int r = 0; r < 32; ++r) a += ((r >> k) & 1) ? -v[r] : v[r];
        s5[k] = a;
    }

    // low-pressure LDS reduction, then one atomic per qubit (22 parallel lanes)
    __syncthreads();                       // all reads of chunk done before reuse
    chunk[t] = tot;
#pragma unroll
    for (int k = 0; k < 5; ++k) chunk[256 + k * 256 + t] = s5[k];
    __syncthreads();

    if (t < NQ) {
        const int q = t;
        float val = 0.f;
        if (q < 9) {                       // h bit (8-q), uniform sign over block
            for (int tt = 0; tt < 256; ++tt) val += chunk[tt];
            if ((h >> (8 - q)) & 1) val = -val;
        } else if (q < 17) {               // t-bit i = 16-q of tot
            const int i = 16 - q;
            for (int tt = 0; tt < 256; ++tt)
                val += ((tt >> i) & 1) ? -chunk[tt] : chunk[tt];
        } else {                           // reg bit k = 21-q
            const int k = 21 - q;
            for (int tt = 0; tt < 256; ++tt) val += chunk[256 + k * 256 + tt];
        }
        atomicAdd(&out[q], val);
    }
}

extern "C" void kernel_launch(void* const* d_in, const int* in_sizes, int n_in,
                              void* d_out, int out_size, void* d_ws, size_t ws_size,
                              hipStream_t stream) {
    const float* feat   = (const float*)d_in[0];   // 22
    const float* adj    = (const float*)d_in[1];   // 22*22
    const float* params = (const float*)d_in[2];   // 3*22
    float* out = (float*)d_out;                    // 22 f32

    char* ws = (char*)d_ws;
    float*    state  = (float*)ws;                              // 4M floats = 16 MB
    float*    w      = (float*)(ws + ((size_t)1 << 24));        // 512
    float*    u      = w + HD;                                  // 8192
    unsigned* sigh   = (unsigned*)(u + LD);                     // 512
    unsigned* lowvs  = sigh + HD;                               // 8192
    float2*   cs1    = (float2*)(lowvs + LD);                   // 22
    float2*   cs2    = cs1 + NQ;                                // 22

    k0_tables<<<dim3(32), dim3(256), 0, stream>>>(feat, adj, params, w, u, sigh, lowvs,
                                                  cs1, cs2, out);
    kA<<<dim3(512), dim3(256), 0, stream>>>(state, w, u, sigh, lowvs, cs1);
    kB<<<dim3(512), dim3(256), 0, stream>>>(state, sigh, lowvs, cs1, cs2);
    kC<<<dim3(512), dim3(256), 0, stream>>>(state, cs2, out);
}

// Round 5
// 111.804 us; speedup vs baseline: 2.0156x; 1.1674x over previous
//
#include <hip/hip_runtime.h>
#include <math.h>

#define NQ 22
#define NH 9        // high qubits 0..8   (h = x >> 13)
#define NL 13       // low qubits 9..21   (l = x & 8191)
#define HD 512
#define LD 8192

// In-register butterfly over register-index bit K (32 regs -> 16 pairs).
template<int K>
__device__ __forceinline__ void bfly32(float v[32], float2 cc) {
    const float c = cc.x, s = cc.y;
#pragma unroll
    for (int p = 0; p < 16; ++p) {
        int i0 = ((p >> K) << (K + 1)) | (p & ((1 << K) - 1));
        int i1 = i0 | (1 << K);
        float a = v[i0], b = v[i1];
        v[i0] = c * a - s * b;
        v[i1] = s * a + c * b;
    }
}

// ---------------- k0: tables via per-qubit bitmasks + popc ----------------
// blocks 0..31: low tables u[8192], lowvs[8192]; block 32: w/sigh; block 33: cs + out=0
__global__ __launch_bounds__(256) void k0_tables(
        const float* feat, const float* adj, const float* params,
        float* w, float* u, unsigned* sigh, unsigned* lowvs,
        float2* cs1, float2* cs2, float* out) {
    __shared__ unsigned s_m[32];
    __shared__ float2 s_cs[16];
    const int b = blockIdx.x, t = threadIdx.x;

    if (b < 32) {
        // s_m[0..8] = cross masks (high i vs low), s_m[9..21] = strict low-low
        if (t < 9) {
            unsigned m = 0;
            for (int qj = 0; qj < 13; ++qj)
                if (adj[t * NQ + 9 + qj] > 0.f) m |= 1u << (12 - qj);
            s_m[t] = m;
        } else if (t < 22) {
            int qi = t - 9;
            unsigned m = 0;
            for (int qj = qi + 1; qj < 13; ++qj)
                if (adj[(9 + qi) * NQ + 9 + qj] > 0.f) m |= 1u << (12 - qj);
            s_m[t] = m;
        } else if (t < 35) {
            int q = 9 + (t - 22);
            float a = 0.5f * (feat[q] + params[q]);
            s_cs[t - 22] = make_float2(cosf(a), sinf(a));
        }
        __syncthreads();
        int l = b * 256 + t;
        float prod = 1.f;
        unsigned sl = 0;
#pragma unroll
        for (int qi = 0; qi < 13; ++qi) {
            int bit = (l >> (12 - qi)) & 1;
            float2 cp = s_cs[qi];
            prod *= bit ? cp.y : cp.x;
            sl ^= (unsigned)(bit & (__popc(l & s_m[9 + qi]) & 1));
        }
        unsigned V = 0;
#pragma unroll
        for (int i = 0; i < 9; ++i)
            V |= (unsigned)(__popc(l & s_m[i]) & 1) << (8 - i);
        u[l] = prod;
        lowvs[l] = V | (sl << NH);
    } else if (b == 32) {
        // strict high-high masks + high (cos,sin)
        if (t < 9) {
            unsigned m = 0;
            for (int j2 = t + 1; j2 < 9; ++j2)
                if (adj[t * NQ + j2] > 0.f) m |= 1u << (8 - j2);
            s_m[t] = m;
            float a = 0.5f * (feat[t] + params[t]);
            s_cs[t] = make_float2(cosf(a), sinf(a));
        }
        __syncthreads();
        for (int h = t; h < HD; h += 256) {
            float prod = 1.f;
            unsigned sg = 0;
#pragma unroll
            for (int i = 0; i < 9; ++i) {
                int bit = (h >> (8 - i)) & 1;
                float2 cp = s_cs[i];
                prod *= bit ? cp.y : cp.x;
                sg ^= (unsigned)(bit & (__popc(h & s_m[i]) & 1));
            }
            w[h] = prod;
            sigh[h] = sg;
        }
    } else {
        if (t < NQ) {
            cs1[t] = make_float2(cosf(0.5f * params[NQ + t]),   sinf(0.5f * params[NQ + t]));
            cs2[t] = make_float2(cosf(0.5f * params[2*NQ + t]), sinf(0.5f * params[2*NQ + t]));
            out[t] = 0.f;     // kC accumulates atomically; harness poisons d_out
        }
    }
}

// ---------------- kA: init (feat+p0+sign analytic) + layer-1 low ----------
// Mappings (l within the 8192-chunk of row h), thread t, reg r:
//   A : l = r + 32*t                 (reg bits = l bits 0-4, qubits 21..17)
//   B : l = (t&31)+32*r+1024*(t>>5)  (reg bits = l bits 5-9, qubits 16..12)
//   C': l = 4*t + (r&3) + 1024*(r>>2)(reg bits 2-4 = l bits 10-12, qubits 11..9)
// LDS layout f(l) = l + (l>>5)  (all mapped patterns <=2-way conflict: free)
// launch_bounds (256,4): 128-VGPR cap -- v[32] must stay in registers (R2: 1-arg
// bounds capped at ~52 VGPR and spilled -> 2x slowdown).
__global__ __launch_bounds__(256, 4) void kA(float* state, const float* w, const float* u,
                                             const unsigned* sigh, const unsigned* lowvs,
                                             const float2* cs1) {
    __shared__ float chunk[8448];
    const int h = blockIdx.x, t = threadIdx.x;

#pragma unroll
    for (int it = 0; it < 32; ++it) {
        int i = t + 256 * it;
        unsigned lv = lowvs[i];
        float uv = u[i];
        unsigned sgn = ((lv >> NH) ^ (unsigned)__popc(h & (lv & 511u))) & 1u;
        chunk[i + (i >> 5)] = sgn ? -uv : uv;
    }
    float whs = sigh[h] ? -w[h] : w[h];
    __syncthreads();

    float v[32];
#pragma unroll
    for (int r = 0; r < 32; ++r) v[r] = whs * chunk[r + 33 * t];   // mapping A

    bfly32<0>(v, cs1[21]); bfly32<1>(v, cs1[20]); bfly32<2>(v, cs1[19]);
    bfly32<3>(v, cs1[18]); bfly32<4>(v, cs1[17]);

    __syncthreads();
#pragma unroll
    for (int r = 0; r < 32; ++r) chunk[r + 33 * t] = v[r];
    __syncthreads();
    const int t5 = t & 31, th = t >> 5;
#pragma unroll
    for (int r = 0; r < 32; ++r) v[r] = chunk[t5 + 33 * r + 1056 * th];  // mapping B

    bfly32<0>(v, cs1[16]); bfly32<1>(v, cs1[15]); bfly32<2>(v, cs1[14]);
    bfly32<3>(v, cs1[13]); bfly32<4>(v, cs1[12]);

    __syncthreads();
#pragma unroll
    for (int r = 0; r < 32; ++r) chunk[t5 + 33 * r + 1056 * th] = v[r];
    __syncthreads();
#pragma unroll
    for (int r = 0; r < 32; ++r) {
        int l = 4 * t + (r & 3) + 1024 * (r >> 2);                  // mapping C'
        v[r] = chunk[l + (l >> 5)];
    }

    bfly32<2>(v, cs1[11]); bfly32<3>(v, cs1[10]); bfly32<4>(v, cs1[9]);

    float4* sp = (float4*)(state + (size_t)h * LD + 4 * t);
#pragma unroll
    for (int r5 = 0; r5 < 8; ++r5)
        sp[r5 * 256] = make_float4(v[4*r5], v[4*r5+1], v[4*r5+2], v[4*r5+3]);
}

// ---------------- kB: layer-1 high + sign + layer-2 high (fused column pass) ----------
// beta : m = (r&15) + 16*g + 256*(r>>4)  (reg bits = m bits {0,1,2,3,8})
//        fixed r: lanes differ by m-stride 16 -> 17*16 = 16 mod 32 -> 2-way, free
//        (R3's m = r+32g collapsed g-lanes to one bank: 17*32 = 0 mod 32 -> 4-way)
// alpha: m = g + 16*r                    (reg bits = m bits 4-8)
__global__ __launch_bounds__(256, 4) void kB(float* state, const unsigned* sigh,
                                             const unsigned* lowvs,
                                             const float2* cs1, const float2* cs2) {
    __shared__ float tile[8704];
    __shared__ unsigned sgh[HD];
    const int t = threadIdx.x;
    const int j = t & 15, g = t >> 4;
    const int rb = blockIdx.x * 16;

    sgh[t] = sigh[t]; sgh[t + 256] = sigh[t + 256];

    float v[32];
    const float* gp = state + rb + j;
#pragma unroll
    for (int r = 0; r < 32; ++r) {
        int m = (r & 15) + 16 * g + 256 * (r >> 4);
        v[r] = gp[(size_t)m * LD];
    }
    // layer-1 high, qubits 8..5 = m bits 0..3 = reg bits 0..3
    bfly32<0>(v, cs1[8]); bfly32<1>(v, cs1[7]); bfly32<2>(v, cs1[6]); bfly32<3>(v, cs1[5]);

    __syncthreads();   // also covers sgh staging
#pragma unroll
    for (int r = 0; r < 32; ++r) {
        int m = (r & 15) + 16 * g + 256 * (r >> 4);
        tile[m * 17 + j] = v[r];
    }
    __syncthreads();
#pragma unroll
    for (int r = 0; r < 32; ++r) v[r] = tile[(g + 16 * r) * 17 + j];   // alpha

    // layer-1 high, qubits 4..0 = m bits 4..8 = reg bits 0..4
    bfly32<0>(v, cs1[4]); bfly32<1>(v, cs1[3]); bfly32<2>(v, cs1[2]);
    bfly32<3>(v, cs1[1]); bfly32<4>(v, cs1[0]);

    {   // sign between layers
        unsigned lv = lowvs[rb + j];
        unsigned V = lv & 511u, sl = (lv >> NH) & 1u;
#pragma unroll
        for (int r = 0; r < 32; ++r) {
            int m = g + 16 * r;
            unsigned sgn = (sgh[m] ^ sl ^ (unsigned)__popc((unsigned)m & V)) & 1u;
            if (sgn) v[r] = -v[r];
        }
    }

    // layer-2 high, alpha part
    bfly32<0>(v, cs2[4]); bfly32<1>(v, cs2[3]); bfly32<2>(v, cs2[2]);
    bfly32<3>(v, cs2[1]); bfly32<4>(v, cs2[0]);

    __syncthreads();
#pragma unroll
    for (int r = 0; r < 32; ++r) tile[(g + 16 * r) * 17 + j] = v[r];
    __syncthreads();
#pragma unroll
    for (int r = 0; r < 32; ++r) {
        int m = (r & 15) + 16 * g + 256 * (r >> 4);
        v[r] = tile[m * 17 + j];                                       // beta
    }
    // layer-2 high, beta part
    bfly32<0>(v, cs2[8]); bfly32<1>(v, cs2[7]); bfly32<2>(v, cs2[6]); bfly32<3>(v, cs2[5]);

    float* op = state + rb + j;
#pragma unroll
    for (int r = 0; r < 32; ++r) {
        int m = (r & 15) + 16 * g + 256 * (r >> 4);
        op[(size_t)m * LD] = v[r];
    }
}

// ---------------- kC: layer-2 low + probs + 22 expectation partials ----------
__global__ __launch_bounds__(256, 4) void kC(const float* state, const float2* cs2, float* out) {
    __shared__ float chunk[8448];
    const int h = blockIdx.x, t = threadIdx.x;

    float v[32];
    const float4* sp = (const float4*)(state + (size_t)h * LD + 4 * t);
#pragma unroll
    for (int r5 = 0; r5 < 8; ++r5) {
        float4 x = sp[r5 * 256];
        v[4*r5] = x.x; v[4*r5+1] = x.y; v[4*r5+2] = x.z; v[4*r5+3] = x.w;  // C'
    }

    bfly32<2>(v, cs2[11]); bfly32<3>(v, cs2[10]); bfly32<4>(v, cs2[9]);

#pragma unroll
    for (int r = 0; r < 32; ++r) {
        int l = 4 * t + (r & 3) + 1024 * (r >> 2);
        chunk[l + (l >> 5)] = v[r];
    }
    __syncthreads();
    const int t5 = t & 31, th = t >> 5;
#pragma unroll
    for (int r = 0; r < 32; ++r) v[r] = chunk[t5 + 33 * r + 1056 * th];  // B

    bfly32<0>(v, cs2[16]); bfly32<1>(v, cs2[15]); bfly32<2>(v, cs2[14]);
    bfly32<3>(v, cs2[13]); bfly32<4>(v, cs2[12]);

    __syncthreads();
#pragma unroll
    for (int r = 0; r < 32; ++r) chunk[t5 + 33 * r + 1056 * th] = v[r];
    __syncthreads();
#pragma unroll
    for (int r = 0; r < 32; ++r) v[r] = chunk[r + 33 * t];               // A: l = r + 32t

    bfly32<0>(v, cs2[21]); bfly32<1>(v, cs2[20]); bfly32<2>(v, cs2[19]);
    bfly32<3>(v, cs2[18]); bfly32<4>(v, cs2[17]);

    // probs + per-thread partials (6 live floats; v dead after)
#pragma unroll
    for (int r = 0; r < 32; ++r) v[r] = v[r] * v[r];
    float tot = 0.f;
#pragma unroll
    for (int r = 0; r < 32; ++r) tot += v[r];
    float s5[5];
#pragma unroll
    for (int k = 0; k < 5; ++k) {
        float a = 0.f;
#pragma unroll
        for (int r = 0; r < 32; ++r) a += ((r >> k) & 1) ? -v[r] : v[r];
        s5[k] = a;
    }

    // low-pressure LDS reduction, then one atomic per qubit (22 parallel lanes)
    __syncthreads();                       // all reads of chunk done before reuse
    chunk[t] = tot;
#pragma unroll
    for (int k = 0; k < 5; ++k) chunk[256 + k * 256 + t] = s5[k];
    __syncthreads();

    if (t < NQ) {
        const int q = t;
        float val = 0.f;
        if (q < 9) {                       // h bit (8-q), uniform sign over block
            for (int tt = 0; tt < 256; ++tt) val += chunk[tt];
            if ((h >> (8 - q)) & 1) val = -val;
        } else if (q < 17) {               // t-bit i = 16-q of tot
            const int i = 16 - q;
            for (int tt = 0; tt < 256; ++tt)
                val += ((tt >> i) & 1) ? -chunk[tt] : chunk[tt];
        } else {                           // reg bit k = 21-q
            const int k = 21 - q;
            for (int tt = 0; tt < 256; ++tt) val += chunk[256 + k * 256 + tt];
        }
        atomicAdd(&out[q], val);
    }
}

extern "C" void kernel_launch(void* const* d_in, const int* in_sizes, int n_in,
                              void* d_out, int out_size, void* d_ws, size_t ws_size,
                              hipStream_t stream) {
    const float* feat   = (const float*)d_in[0];   // 22
    const float* adj    = (const float*)d_in[1];   // 22*22
    const float* params = (const float*)d_in[2];   // 3*22
    float* out = (float*)d_out;                    // 22 f32

    char* ws = (char*)d_ws;
    float*    state  = (float*)ws;                              // 16 MB
    float*    w      = (float*)(ws + ((size_t)1 << 24));        // 512
    float*    u      = w + HD;                                  // 8192
    unsigned* sigh   = (unsigned*)(u + LD);                     // 512
    unsigned* lowvs  = sigh + HD;                               // 8192
    float2*   cs1    = (float2*)(lowvs + LD);                   // 22
    float2*   cs2    = cs1 + NQ;                                // 22

    k0_tables<<<dim3(34), dim3(256), 0, stream>>>(feat, adj, params, w, u, sigh, lowvs,
                                                  cs1, cs2, out);
    kA<<<dim3(512), dim3(256), 0, stream>>>(state, w, u, sigh, lowvs, cs1);
    kB<<<dim3(512), dim3(256), 0, stream>>>(state, sigh, lowvs, cs1, cs2);
    kC<<<dim3(512), dim3(256), 0, stream>>>(state, cs2, out);
}

// Round 6
// 108.065 us; speedup vs baseline: 2.0853x; 1.0346x over previous
//
#include <hip/hip_runtime.h>
#include <math.h>

#define NQ 22
#define NH 9        // high qubits 0..8   (h = x >> 13)
#define NL 13       // low qubits 9..21   (l = x & 8191)
#define HD 512
#define LD 8192
#define RS 8224     // state row stride in floats: 32896 B = 257*128 B (odd multiple
                    // of the cache line) -- rotates L2-channel/HBM-bank mapping per
                    // row; a 2^15 B stride put every column segment on one channel.

// In-register butterfly over register-index bit K (32 regs -> 16 pairs).
template<int K>
__device__ __forceinline__ void bfly32(float v[32], float2 cc) {
    const float c = cc.x, s = cc.y;
#pragma unroll
    for (int p = 0; p < 16; ++p) {
        int i0 = ((p >> K) << (K + 1)) | (p & ((1 << K) - 1));
        int i1 = i0 | (1 << K);
        float a = v[i0], b = v[i1];
        v[i0] = c * a - s * b;
        v[i1] = s * a + c * b;
    }
}

// ---------------- k0: tables via per-qubit bitmasks + popc ----------------
__global__ __launch_bounds__(256) void k0_tables(
        const float* feat, const float* adj, const float* params,
        float* w, float* u, unsigned* sigh, unsigned* lowvs,
        float2* cs1, float2* cs2, float* out) {
    __shared__ unsigned s_m[32];
    __shared__ float2 s_cs[16];
    const int b = blockIdx.x, t = threadIdx.x;

    if (b < 32) {
        if (t < 9) {
            unsigned m = 0;
            for (int qj = 0; qj < 13; ++qj)
                if (adj[t * NQ + 9 + qj] > 0.f) m |= 1u << (12 - qj);
            s_m[t] = m;
        } else if (t < 22) {
            int qi = t - 9;
            unsigned m = 0;
            for (int qj = qi + 1; qj < 13; ++qj)
                if (adj[(9 + qi) * NQ + 9 + qj] > 0.f) m |= 1u << (12 - qj);
            s_m[t] = m;
        } else if (t < 35) {
            int q = 9 + (t - 22);
            float a = 0.5f * (feat[q] + params[q]);
            s_cs[t - 22] = make_float2(cosf(a), sinf(a));
        }
        __syncthreads();
        int l = b * 256 + t;
        float prod = 1.f;
        unsigned sl = 0;
#pragma unroll
        for (int qi = 0; qi < 13; ++qi) {
            int bit = (l >> (12 - qi)) & 1;
            float2 cp = s_cs[qi];
            prod *= bit ? cp.y : cp.x;
            sl ^= (unsigned)(bit & (__popc(l & s_m[9 + qi]) & 1));
        }
        unsigned V = 0;
#pragma unroll
        for (int i = 0; i < 9; ++i)
            V |= (unsigned)(__popc(l & s_m[i]) & 1) << (8 - i);
        u[l] = prod;
        lowvs[l] = V | (sl << NH);
    } else if (b == 32) {
        if (t < 9) {
            unsigned m = 0;
            for (int j2 = t + 1; j2 < 9; ++j2)
                if (adj[t * NQ + j2] > 0.f) m |= 1u << (8 - j2);
            s_m[t] = m;
            float a = 0.5f * (feat[t] + params[t]);
            s_cs[t] = make_float2(cosf(a), sinf(a));
        }
        __syncthreads();
        for (int h = t; h < HD; h += 256) {
            float prod = 1.f;
            unsigned sg = 0;
#pragma unroll
            for (int i = 0; i < 9; ++i) {
                int bit = (h >> (8 - i)) & 1;
                float2 cp = s_cs[i];
                prod *= bit ? cp.y : cp.x;
                sg ^= (unsigned)(bit & (__popc(h & s_m[i]) & 1));
            }
            w[h] = prod;
            sigh[h] = sg;
        }
    } else {
        if (t < NQ) {
            cs1[t] = make_float2(cosf(0.5f * params[NQ + t]),   sinf(0.5f * params[NQ + t]));
            cs2[t] = make_float2(cosf(0.5f * params[2*NQ + t]), sinf(0.5f * params[2*NQ + t]));
            out[t] = 0.f;
        }
    }
}

// ---------------- kA: init (feat+p0+sign analytic) + layer-1 low ----------
// Mappings (l within the 8192-chunk of row h), thread t, reg r:
//   A : l = r + 32*t                 (reg bits = l bits 0-4, qubits 21..17)
//   B : l = (t&31)+32*r+1024*(t>>5)  (reg bits = l bits 5-9, qubits 16..12)
//   C': l = 4*t + (r&3) + 1024*(r>>2)(reg bits 2-4 = l bits 10-12, qubits 11..9)
// LDS layout f(l) = l + (l>>5)  (all mapped patterns <=2-way conflict: free)
// launch_bounds (256,4): 128-VGPR cap -- v[32] must stay in registers (R2: 1-arg
// bounds capped at ~52 VGPR and spilled -> 2x slowdown).
__global__ __launch_bounds__(256, 4) void kA(float* state, const float* w, const float* u,
                                             const unsigned* sigh, const unsigned* lowvs,
                                             const float2* cs1) {
    __shared__ float chunk[8448];
    const int h = blockIdx.x, t = threadIdx.x;

#pragma unroll
    for (int it = 0; it < 32; ++it) {
        int i = t + 256 * it;
        unsigned lv = lowvs[i];
        float uv = u[i];
        unsigned sgn = ((lv >> NH) ^ (unsigned)__popc(h & (lv & 511u))) & 1u;
        chunk[i + (i >> 5)] = sgn ? -uv : uv;
    }
    float whs = sigh[h] ? -w[h] : w[h];
    __syncthreads();

    float v[32];
#pragma unroll
    for (int r = 0; r < 32; ++r) v[r] = whs * chunk[r + 33 * t];   // mapping A

    bfly32<0>(v, cs1[21]); bfly32<1>(v, cs1[20]); bfly32<2>(v, cs1[19]);
    bfly32<3>(v, cs1[18]); bfly32<4>(v, cs1[17]);

    __syncthreads();
#pragma unroll
    for (int r = 0; r < 32; ++r) chunk[r + 33 * t] = v[r];
    __syncthreads();
    const int t5 = t & 31, th = t >> 5;
#pragma unroll
    for (int r = 0; r < 32; ++r) v[r] = chunk[t5 + 33 * r + 1056 * th];  // mapping B

    bfly32<0>(v, cs1[16]); bfly32<1>(v, cs1[15]); bfly32<2>(v, cs1[14]);
    bfly32<3>(v, cs1[13]); bfly32<4>(v, cs1[12]);

    __syncthreads();
#pragma unroll
    for (int r = 0; r < 32; ++r) chunk[t5 + 33 * r + 1056 * th] = v[r];
    __syncthreads();
#pragma unroll
    for (int r = 0; r < 32; ++r) {
        int l = 4 * t + (r & 3) + 1024 * (r >> 2);                  // mapping C'
        v[r] = chunk[l + (l >> 5)];
    }

    bfly32<2>(v, cs1[11]); bfly32<3>(v, cs1[10]); bfly32<4>(v, cs1[9]);

    float4* sp = (float4*)(state + (size_t)h * RS + 4 * t);
#pragma unroll
    for (int r5 = 0; r5 < 8; ++r5)
        sp[r5 * 256] = make_float4(v[4*r5], v[4*r5+1], v[4*r5+2], v[4*r5+3]);
}

// ---------------- kB: layer-1 high + sign + layer-2 high (fused column pass) ----------
// beta : m = (r&15) + 16*g + 256*(r>>4)  (reg bits = m bits {0,1,2,3,8})
//        fixed r: lanes differ by m-stride 16 -> 17*16 = 16 mod 32 -> 2-way, free
// alpha: m = g + 16*r                    (reg bits = m bits 4-8)
// Column swizzle: rbIdx = (b&7)*64 + (b>>3) -- the two blocks sharing each 128 B
// line (col pairs 2j,2j+1) differ by 8 in b -> same XCD (dispatch b%8), so each
// line is fetched once per XCD L2 instead of twice via LLC.
__global__ __launch_bounds__(256, 4) void kB(float* state, const unsigned* sigh,
                                             const unsigned* lowvs,
                                             const float2* cs1, const float2* cs2) {
    __shared__ float tile[8704];
    __shared__ unsigned sgh[HD];
    const int t = threadIdx.x;
    const int j = t & 15, g = t >> 4;
    const int b = blockIdx.x;
    const int rb = ((b & 7) * 64 + (b >> 3)) * 16;

    sgh[t] = sigh[t]; sgh[t + 256] = sigh[t + 256];

    float v[32];
    const float* gp = state + rb + j;
#pragma unroll
    for (int r = 0; r < 32; ++r) {
        int m = (r & 15) + 16 * g + 256 * (r >> 4);
        v[r] = gp[(size_t)m * RS];
    }
    // layer-1 high, qubits 8..5 = m bits 0..3 = reg bits 0..3
    bfly32<0>(v, cs1[8]); bfly32<1>(v, cs1[7]); bfly32<2>(v, cs1[6]); bfly32<3>(v, cs1[5]);

    __syncthreads();   // also covers sgh staging
#pragma unroll
    for (int r = 0; r < 32; ++r) {
        int m = (r & 15) + 16 * g + 256 * (r >> 4);
        tile[m * 17 + j] = v[r];
    }
    __syncthreads();
#pragma unroll
    for (int r = 0; r < 32; ++r) v[r] = tile[(g + 16 * r) * 17 + j];   // alpha

    // layer-1 high, qubits 4..0 = m bits 4..8 = reg bits 0..4
    bfly32<0>(v, cs1[4]); bfly32<1>(v, cs1[3]); bfly32<2>(v, cs1[2]);
    bfly32<3>(v, cs1[1]); bfly32<4>(v, cs1[0]);

    {   // sign between layers
        unsigned lv = lowvs[rb + j];
        unsigned V = lv & 511u, sl = (lv >> NH) & 1u;
#pragma unroll
        for (int r = 0; r < 32; ++r) {
            int m = g + 16 * r;
            unsigned sgn = (sgh[m] ^ sl ^ (unsigned)__popc((unsigned)m & V)) & 1u;
            if (sgn) v[r] = -v[r];
        }
    }

    // layer-2 high, alpha part
    bfly32<0>(v, cs2[4]); bfly32<1>(v, cs2[3]); bfly32<2>(v, cs2[2]);
    bfly32<3>(v, cs2[1]); bfly32<4>(v, cs2[0]);

    __syncthreads();
#pragma unroll
    for (int r = 0; r < 32; ++r) tile[(g + 16 * r) * 17 + j] = v[r];
    __syncthreads();
#pragma unroll
    for (int r = 0; r < 32; ++r) {
        int m = (r & 15) + 16 * g + 256 * (r >> 4);
        v[r] = tile[m * 17 + j];                                       // beta
    }
    // layer-2 high, beta part
    bfly32<0>(v, cs2[8]); bfly32<1>(v, cs2[7]); bfly32<2>(v, cs2[6]); bfly32<3>(v, cs2[5]);

    float* op = state + rb + j;
#pragma unroll
    for (int r = 0; r < 32; ++r) {
        int m = (r & 15) + 16 * g + 256 * (r >> 4);
        op[(size_t)m * RS] = v[r];
    }
}

// ---------------- kC: layer-2 low + probs + 22 expectation partials ----------
__global__ __launch_bounds__(256, 4) void kC(const float* state, const float2* cs2, float* out) {
    __shared__ float chunk[8448];
    const int h = blockIdx.x, t = threadIdx.x;

    float v[32];
    const float4* sp = (const float4*)(state + (size_t)h * RS + 4 * t);
#pragma unroll
    for (int r5 = 0; r5 < 8; ++r5) {
        float4 x = sp[r5 * 256];
        v[4*r5] = x.x; v[4*r5+1] = x.y; v[4*r5+2] = x.z; v[4*r5+3] = x.w;  // C'
    }

    bfly32<2>(v, cs2[11]); bfly32<3>(v, cs2[10]); bfly32<4>(v, cs2[9]);

#pragma unroll
    for (int r = 0; r < 32; ++r) {
        int l = 4 * t + (r & 3) + 1024 * (r >> 2);
        chunk[l + (l >> 5)] = v[r];
    }
    __syncthreads();
    const int t5 = t & 31, th = t >> 5;
#pragma unroll
    for (int r = 0; r < 32; ++r) v[r] = chunk[t5 + 33 * r + 1056 * th];  // B

    bfly32<0>(v, cs2[16]); bfly32<1>(v, cs2[15]); bfly32<2>(v, cs2[14]);
    bfly32<3>(v, cs2[13]); bfly32<4>(v, cs2[12]);

    __syncthreads();
#pragma unroll
    for (int r = 0; r < 32; ++r) chunk[t5 + 33 * r + 1056 * th] = v[r];
    __syncthreads();
#pragma unroll
    for (int r = 0; r < 32; ++r) v[r] = chunk[r + 33 * t];               // A: l = r + 32t

    bfly32<0>(v, cs2[21]); bfly32<1>(v, cs2[20]); bfly32<2>(v, cs2[19]);
    bfly32<3>(v, cs2[18]); bfly32<4>(v, cs2[17]);

    // probs + per-thread partials (6 live floats; v dead after)
#pragma unroll
    for (int r = 0; r < 32; ++r) v[r] = v[r] * v[r];
    float tot = 0.f;
#pragma unroll
    for (int r = 0; r < 32; ++r) tot += v[r];
    float s5[5];
#pragma unroll
    for (int k = 0; k < 5; ++k) {
        float a = 0.f;
#pragma unroll
        for (int r = 0; r < 32; ++r) a += ((r >> k) & 1) ? -v[r] : v[r];
        s5[k] = a;
    }

    // low-pressure LDS reduction, then one atomic per qubit (22 parallel lanes)
    __syncthreads();
    chunk[t] = tot;
#pragma unroll
    for (int k = 0; k < 5; ++k) chunk[256 + k * 256 + t] = s5[k];
    __syncthreads();

    if (t < NQ) {
        const int q = t;
        float val = 0.f;
        if (q < 9) {
            for (int tt = 0; tt < 256; ++tt) val += chunk[tt];
            if ((h >> (8 - q)) & 1) val = -val;
        } else if (q < 17) {
            const int i = 16 - q;
            for (int tt = 0; tt < 256; ++tt)
                val += ((tt >> i) & 1) ? -chunk[tt] : chunk[tt];
        } else {
            const int k = 21 - q;
            for (int tt = 0; tt < 256; ++tt) val += chunk[256 + k * 256 + tt];
        }
        atomicAdd(&out[q], val);
    }
}

extern "C" void kernel_launch(void* const* d_in, const int* in_sizes, int n_in,
                              void* d_out, int out_size, void* d_ws, size_t ws_size,
                              hipStream_t stream) {
    const float* feat   = (const float*)d_in[0];   // 22
    const float* adj    = (const float*)d_in[1];   // 22*22
    const float* params = (const float*)d_in[2];   // 3*22
    float* out = (float*)d_out;                    // 22 f32

    char* ws = (char*)d_ws;
    float*    state  = (float*)ws;                              // 512*8224 floats ~ 16.05 MB
    float*    w      = (float*)(ws + ((size_t)18 << 20));       // 512
    float*    u      = w + HD;                                  // 8192
    unsigned* sigh   = (unsigned*)(u + LD);                     // 512
    unsigned* lowvs  = sigh + HD;                               // 8192
    float2*   cs1    = (float2*)(lowvs + LD);                   // 22
    float2*   cs2    = cs1 + NQ;                                // 22

    k0_tables<<<dim3(34), dim3(256), 0, stream>>>(feat, adj, params, w, u, sigh, lowvs,
                                                  cs1, cs2, out);
    kA<<<dim3(512), dim3(256), 0, stream>>>(state, w, u, sigh, lowvs, cs1);
    kB<<<dim3(512), dim3(256), 0, stream>>>(state, sigh, lowvs, cs1, cs2);
    kC<<<dim3(512), dim3(256), 0, stream>>>(state, cs2, out);
}